// Round 2
// baseline (70.352 us; speedup 1.0000x reference)
//
#include <hip/hip_runtime.h>

// ContrastiveCenterLoss on MI355X — round 2.
// B=2048, D=512, C=100, fp32. Scalar loss out.
//
// Algebra (no (B,C) matrix):
//   total = C*Sf2 + B*Sc2 - 2*dot(sumF,sumC)
//   intra = sum_b (||f_b||^2 + ||c_lab||^2 - 2 f_b.c_lab)
//   loss  = 0.5/B * intra / (total - intra + 1e-6) / 0.1
//
// No global atomics → no ws pre-zeroing → no memset dispatch.
// Kernel 1: FB feat-blocks + WB weight-blocks, each writes a private slot:
//   slot s (SLOT=520 floats): [0..511] partial column-sum, [512] partial
//   sum-of-squares, [513] partial intra (feat blocks only).
// Kernel 2: one block of 512 threads reduces all slots and emits the loss.

#define SLOT 520

__global__ __launch_bounds__(256) void ccl_main(
        const float* __restrict__ feat,
        const float* __restrict__ weight,
        const int*   __restrict__ label,
        float* __restrict__ ws,
        int B, int C, int featBlocks, int weightBlocks)
{
    __shared__ float lsum[4][512];
    __shared__ float sscal[4][2];   // [wave][0]=intra, [wave][1]=sum-of-squares

    const int tid  = threadIdx.x;
    const int lane = tid & 63;
    const int wave = tid >> 6;

    // per-lane column accumulators: dims 4*lane+k and 256+4*lane+k
    float acc0 = 0.f, acc1 = 0.f, acc2 = 0.f, acc3 = 0.f;
    float acc4 = 0.f, acc5 = 0.f, acc6 = 0.f, acc7 = 0.f;
    float s2_l    = 0.f;   // per-lane partial of Sf2 (or Sc2)
    float intra_l = 0.f;   // per-lane partial of intra (feat only)

    const bool isFeat = (int)blockIdx.x < featBlocks;

    if (isFeat) {
        const int wavesTotal = featBlocks * 4;
        const int gwave      = blockIdx.x * 4 + wave;
        for (int row = gwave; row < B; row += wavesTotal) {
            const float4* fr = (const float4*)(feat + (size_t)row * 512);
            float4 a = fr[lane];
            float4 b = fr[lane + 64];
            const int lab = label[row];
            const float4* wr = (const float4*)(weight + (size_t)lab * 512);
            float4 wa = wr[lane];
            float4 wb = wr[lane + 64];

            float f2 = a.x*a.x + a.y*a.y + a.z*a.z + a.w*a.w
                     + b.x*b.x + b.y*b.y + b.z*b.z + b.w*b.w;
            float w2 = wa.x*wa.x + wa.y*wa.y + wa.z*wa.z + wa.w*wa.w
                     + wb.x*wb.x + wb.y*wb.y + wb.z*wb.z + wb.w*wb.w;
            float dt = a.x*wa.x + a.y*wa.y + a.z*wa.z + a.w*wa.w
                     + b.x*wb.x + b.y*wb.y + b.z*wb.z + b.w*wb.w;

            acc0 += a.x; acc1 += a.y; acc2 += a.z; acc3 += a.w;
            acc4 += b.x; acc5 += b.y; acc6 += b.z; acc7 += b.w;
            intra_l += f2 + w2 - 2.f * dt;   // reduce at end, not per row
            s2_l    += f2;
        }
    } else {
        const int wavesTotal = weightBlocks * 4;
        const int gwave      = (blockIdx.x - featBlocks) * 4 + wave;
        for (int row = gwave; row < C; row += wavesTotal) {
            const float4* wr = (const float4*)(weight + (size_t)row * 512);
            float4 a = wr[lane];
            float4 b = wr[lane + 64];
            acc0 += a.x; acc1 += a.y; acc2 += a.z; acc3 += a.w;
            acc4 += b.x; acc5 += b.y; acc6 += b.z; acc7 += b.w;
            s2_l += a.x*a.x + a.y*a.y + a.z*a.z + a.w*a.w
                  + b.x*b.x + b.y*b.y + b.z*b.z + b.w*b.w;
        }
    }

    // single wave-level reduce of the two scalars (once per kernel)
    #pragma unroll
    for (int off = 32; off > 0; off >>= 1) {
        intra_l += __shfl_xor(intra_l, off);
        s2_l    += __shfl_xor(s2_l,    off);
    }
    if (lane == 0) { sscal[wave][0] = intra_l; sscal[wave][1] = s2_l; }

    // column partials: lane l owns dims 4l..4l+3 and 256+4l..256+4l+3
    lsum[wave][4*lane + 0] = acc0;
    lsum[wave][4*lane + 1] = acc1;
    lsum[wave][4*lane + 2] = acc2;
    lsum[wave][4*lane + 3] = acc3;
    lsum[wave][256 + 4*lane + 0] = acc4;
    lsum[wave][256 + 4*lane + 1] = acc5;
    lsum[wave][256 + 4*lane + 2] = acc6;
    lsum[wave][256 + 4*lane + 3] = acc7;
    __syncthreads();

    float* base = ws + (size_t)blockIdx.x * SLOT;
    base[tid]       = lsum[0][tid]       + lsum[1][tid]       + lsum[2][tid]       + lsum[3][tid];
    base[tid + 256] = lsum[0][tid + 256] + lsum[1][tid + 256] + lsum[2][tid + 256] + lsum[3][tid + 256];
    if (tid == 0) {
        base[512] = sscal[0][1] + sscal[1][1] + sscal[2][1] + sscal[3][1];
        base[513] = sscal[0][0] + sscal[1][0] + sscal[2][0] + sscal[3][0];
    }
}

__global__ __launch_bounds__(512) void ccl_final(
        const float* __restrict__ ws, float* __restrict__ out,
        int B, int C, int featBlocks, int weightBlocks)
{
    __shared__ float red[8][4];
    const int tid  = threadIdx.x;   // == column index d in [0,512)
    const int lane = tid & 63;
    const int wv   = tid >> 6;

    float sf = 0.f, sc = 0.f;
    for (int s = 0; s < featBlocks; ++s)
        sf += ws[(size_t)s * SLOT + tid];
    for (int s = featBlocks; s < featBlocks + weightBlocks; ++s)
        sc += ws[(size_t)s * SLOT + tid];
    float prod = sf * sc;

    float sf2 = 0.f, sc2 = 0.f, intra = 0.f;
    if (tid < featBlocks) {
        sf2   = ws[(size_t)tid * SLOT + 512];
        intra = ws[(size_t)tid * SLOT + 513];
    } else if (tid < featBlocks + weightBlocks) {
        sc2   = ws[(size_t)tid * SLOT + 512];
    }

    #pragma unroll
    for (int off = 32; off > 0; off >>= 1) {
        prod  += __shfl_xor(prod,  off);
        sf2   += __shfl_xor(sf2,   off);
        sc2   += __shfl_xor(sc2,   off);
        intra += __shfl_xor(intra, off);
    }
    if (lane == 0) {
        red[wv][0] = prod; red[wv][1] = sf2; red[wv][2] = sc2; red[wv][3] = intra;
    }
    __syncthreads();

    if (tid == 0) {
        float dot = 0.f, Sf2 = 0.f, Sc2 = 0.f, Sin = 0.f;
        #pragma unroll
        for (int w = 0; w < 8; ++w) {
            dot += red[w][0]; Sf2 += red[w][1]; Sc2 += red[w][2]; Sin += red[w][3];
        }
        float total = (float)C * Sf2 + (float)B * Sc2 - 2.f * dot;
        float inter = total - Sin;
        out[0] = 0.5f / (float)B * Sin / (inter + 1e-6f) / 0.1f;
    }
}

extern "C" void kernel_launch(void* const* d_in, const int* in_sizes, int n_in,
                              void* d_out, int out_size, void* d_ws, size_t ws_size,
                              hipStream_t stream) {
    const float* feat   = (const float*)d_in[0];
    const float* weight = (const float*)d_in[1];
    const int*   label  = (const int*)d_in[2];
    float* out = (float*)d_out;
    float* ws  = (float*)d_ws;

    const int B = in_sizes[2];              // 2048
    const int D = in_sizes[0] / B;          // 512 (kernel specialized for 512)
    const int C = in_sizes[1] / D;          // 100
    (void)D;

    const int FEAT_BLOCKS   = 256;          // 1024 waves -> 2 rows each
    const int WEIGHT_BLOCKS = 8;            // 32 waves  -> 3-4 rows each

    ccl_main<<<FEAT_BLOCKS + WEIGHT_BLOCKS, 256, 0, stream>>>(
        feat, weight, label, ws, B, C, FEAT_BLOCKS, WEIGHT_BLOCKS);
    ccl_final<<<1, 512, 0, stream>>>(ws, out, B, C, FEAT_BLOCKS, WEIGHT_BLOCKS);
}

// Round 3
// 14.053 us; speedup vs baseline: 5.0062x; 5.0062x over previous
//
#include <hip/hip_runtime.h>

// ContrastiveCenterLoss on MI355X — round 3.
// B=2048, D=512 (specialized), C=100, fp32. Scalar loss.
//
//   total = C*Sf2 + B*Sc2 - 2*dot(sumF,sumC)
//   intra = sum_b (||f_b||^2 + ||c_lab||^2 - 2 f_b.c_lab)
//   loss  = 0.5/B * intra / (total - intra + 1e-6) / 0.1
//
// Bilinear trick: dot(sumF,sumC) = sum_blocks dot(partialF_block, sumC).
// Every block computes sumC redundantly (weight = 200 KB, L2-resident),
// so each block emits ONE float4 slot {intra, Sf2, dot, Sc2} and the
// final kernel reduces just 128 float4s (2 KB) in one wave.

#define FEAT_BLOCKS 128

__global__ __launch_bounds__(256) void ccl_main(
        const float* __restrict__ feat,
        const float* __restrict__ weight,
        const int*   __restrict__ label,
        float* __restrict__ ws,
        int B, int C)
{
    __shared__ float cc[512];      // sumC (column sums of weight)
    __shared__ float swav[4][4];   // per-wave scalar partials

    const int tid  = threadIdx.x;
    const int lane = tid & 63;
    const int wave = tid >> 6;

    // ---- Phase 0: column sums of weight (redundant per block) + Sc2 ----
    float c0 = 0.f, c1 = 0.f, w2_l = 0.f;
    #pragma unroll 4
    for (int c = 0; c < C; ++c) {
        float wa = weight[(size_t)c * 512 + tid];
        float wb = weight[(size_t)c * 512 + tid + 256];
        c0   += wa;
        c1   += wb;
        w2_l += wa * wa + wb * wb;
    }
    cc[tid]       = c0;
    cc[tid + 256] = c1;
    __syncthreads();

    // ---- Phase A: stream feat rows ----
    // lane owns columns 4*lane+k (acc0..3) and 256+4*lane+k (acc4..7)
    float acc0 = 0.f, acc1 = 0.f, acc2 = 0.f, acc3 = 0.f;
    float acc4 = 0.f, acc5 = 0.f, acc6 = 0.f, acc7 = 0.f;
    float intra_l = 0.f, f2_l = 0.f;

    const int wavesTotal = FEAT_BLOCKS * 4;
    for (int row = (int)blockIdx.x * 4 + wave; row < B; row += wavesTotal) {
        const float4* fr = (const float4*)(feat + (size_t)row * 512);
        float4 a = fr[lane];
        float4 b = fr[lane + 64];
        const int lab = label[row];                     // wave-uniform
        const float4* wr = (const float4*)(weight + (size_t)lab * 512);
        float4 wa = wr[lane];
        float4 wb = wr[lane + 64];

        float f2 = a.x*a.x + a.y*a.y + a.z*a.z + a.w*a.w
                 + b.x*b.x + b.y*b.y + b.z*b.z + b.w*b.w;
        float w2 = wa.x*wa.x + wa.y*wa.y + wa.z*wa.z + wa.w*wa.w
                 + wb.x*wb.x + wb.y*wb.y + wb.z*wb.z + wb.w*wb.w;
        float dt = a.x*wa.x + a.y*wa.y + a.z*wa.z + a.w*wa.w
                 + b.x*wb.x + b.y*wb.y + b.z*wb.z + b.w*wb.w;

        acc0 += a.x; acc1 += a.y; acc2 += a.z; acc3 += a.w;
        acc4 += b.x; acc5 += b.y; acc6 += b.z; acc7 += b.w;
        intra_l += f2 + w2 - 2.f * dt;
        f2_l    += f2;
    }

    // ---- Phase B: this block's dot contribution ----
    const float4* ccv = (const float4*)cc;
    float4 ca = ccv[lane];        // columns 4*lane..4*lane+3
    float4 cb = ccv[lane + 64];   // columns 256+4*lane..
    float dot_l = acc0*ca.x + acc1*ca.y + acc2*ca.z + acc3*ca.w
                + acc4*cb.x + acc5*cb.y + acc6*cb.z + acc7*cb.w;

    #pragma unroll
    for (int off = 32; off > 0; off >>= 1) {
        intra_l += __shfl_xor(intra_l, off);
        f2_l    += __shfl_xor(f2_l,    off);
        dot_l   += __shfl_xor(dot_l,   off);
        w2_l    += __shfl_xor(w2_l,    off);
    }
    if (lane == 0) {
        swav[wave][0] = intra_l;
        swav[wave][1] = f2_l;
        swav[wave][2] = dot_l;
        swav[wave][3] = (blockIdx.x == 0) ? w2_l : 0.f;  // Sc2 from block 0 only
    }
    __syncthreads();

    if (tid == 0) {
        float4 s;
        s.x = swav[0][0] + swav[1][0] + swav[2][0] + swav[3][0];
        s.y = swav[0][1] + swav[1][1] + swav[2][1] + swav[3][1];
        s.z = swav[0][2] + swav[1][2] + swav[2][2] + swav[3][2];
        s.w = swav[0][3] + swav[1][3] + swav[2][3] + swav[3][3];
        ((float4*)ws)[blockIdx.x] = s;
    }
}

__global__ __launch_bounds__(64) void ccl_final(
        const float* __restrict__ ws, float* __restrict__ out,
        int B, int C)
{
    const int lane = threadIdx.x;
    const float4* s = (const float4*)ws;
    float4 a = s[lane];            // slots 0..63
    float4 b = s[lane + 64];       // slots 64..127

    float intra = a.x + b.x;
    float sf2   = a.y + b.y;
    float dot   = a.z + b.z;
    float sc2   = a.w + b.w;

    #pragma unroll
    for (int off = 32; off > 0; off >>= 1) {
        intra += __shfl_xor(intra, off);
        sf2   += __shfl_xor(sf2,   off);
        dot   += __shfl_xor(dot,   off);
        sc2   += __shfl_xor(sc2,   off);
    }
    if (lane == 0) {
        float total = (float)C * sf2 + (float)B * sc2 - 2.f * dot;
        float inter = total - intra;
        out[0] = 0.5f / (float)B * intra / (inter + 1e-6f) / 0.1f;
    }
}

extern "C" void kernel_launch(void* const* d_in, const int* in_sizes, int n_in,
                              void* d_out, int out_size, void* d_ws, size_t ws_size,
                              hipStream_t stream) {
    const float* feat   = (const float*)d_in[0];
    const float* weight = (const float*)d_in[1];
    const int*   label  = (const int*)d_in[2];
    float* out = (float*)d_out;
    float* ws  = (float*)d_ws;

    const int B = in_sizes[2];              // 2048
    const int D = in_sizes[0] / B;          // 512 (kernel specialized for 512)
    const int C = in_sizes[1] / D;          // 100
    (void)D;

    ccl_main<<<FEAT_BLOCKS, 256, 0, stream>>>(feat, weight, label, ws, B, C);
    ccl_final<<<1, 64, 0, stream>>>(ws, out, B, C);
}

// Round 4
// 11.098 us; speedup vs baseline: 6.3395x; 1.2663x over previous
//
#include <hip/hip_runtime.h>

// ContrastiveCenterLoss on MI355X — round 4.
// B=2048, D=512, C=100 (shapes fixed by setup_inputs; kernel specialized).
//
//   total = C*Sf2 + B*Sc2 - 2*dot(sumF,sumC)
//   intra = sum_b (||f_b||^2 + ||c_lab||^2 - 2 f_b.c_lab)
//   loss  = 0.5/B * intra / (total - intra + 1e-6) / 0.1
//
// All loss terms decompose over (row-chunk, column-slice) tiles:
//   grid = 32 row-chunks (64 rows) x 8 col-slices (64 cols) = 256 blocks.
// Block computes 4 scalars {intra, Sf2, dot_partial, Sc2} over its tile:
//   dot_partial = (sum over chunk rows of feat-slice) . (full-weight col-sum
//   of this slice) — bilinear, so summing over row-chunks and slices gives
//   dot(sumF, sumC) exactly. Sc2 contributed by rc==0 blocks only.
// Fully unrolled: every load issues up front; gathers only wait on labels
// (oldest outstanding -> in-order vmcnt retire).

__global__ __launch_bounds__(256) void ccl_main(
        const float* __restrict__ feat,
        const float* __restrict__ weight,
        const int*   __restrict__ label,
        float4* __restrict__ ws)
{
    __shared__ float4 scc[16][16];   // [rowgrp][col4] partial weight col-sums
    __shared__ float  swav[4][4];

    const int t      = threadIdx.x;
    const int lane   = t & 63;
    const int wave   = t >> 6;
    const int col4   = t & 15;       // which float4 within the 64-col slice
    const int rowgrp = t >> 4;       // 16 row groups
    const int rc     = (int)blockIdx.x >> 3;   // row chunk 0..31
    const int cs     = (int)blockIdx.x & 7;    // col slice 0..7
    const int rbase  = rc * 64;
    const int c4     = cs * 16 + col4;         // float4 index within row (128/row)

    const float4* fv = (const float4*)feat;    // [2048][128]
    const float4* wv = (const float4*)weight;  // [100][128]

    // ---- issue all loads up front ----
    const int lab0 = label[rbase + rowgrp];
    const int lab1 = label[rbase + rowgrp + 16];
    const int lab2 = label[rbase + rowgrp + 32];
    const int lab3 = label[rbase + rowgrp + 48];

    const float4 f0 = fv[(size_t)(rbase + rowgrp     ) * 128 + c4];
    const float4 f1 = fv[(size_t)(rbase + rowgrp + 16) * 128 + c4];
    const float4 f2 = fv[(size_t)(rbase + rowgrp + 32) * 128 + c4];
    const float4 f3 = fv[(size_t)(rbase + rowgrp + 48) * 128 + c4];

    // weight col-slice rows rowgrp+16i, i<7 (covers 0..99 once across rowgrps)
    const float4 w0 = wv[(size_t)(rowgrp     ) * 128 + c4];
    const float4 w1 = wv[(size_t)(rowgrp + 16) * 128 + c4];
    const float4 w2 = wv[(size_t)(rowgrp + 32) * 128 + c4];
    const float4 w3 = wv[(size_t)(rowgrp + 48) * 128 + c4];
    const float4 w4 = wv[(size_t)(rowgrp + 64) * 128 + c4];
    const float4 w5 = wv[(size_t)(rowgrp + 80) * 128 + c4];
    float4 w6 = {0.f, 0.f, 0.f, 0.f};
    if (rowgrp < 4)
        w6 = wv[(size_t)(rowgrp + 96) * 128 + c4];

    // gathers (wait only on labels)
    const float4 g0 = wv[(size_t)lab0 * 128 + c4];
    const float4 g1 = wv[(size_t)lab1 * 128 + c4];
    const float4 g2 = wv[(size_t)lab2 * 128 + c4];
    const float4 g3 = wv[(size_t)lab3 * 128 + c4];

    // ---- weight col-sum partial + Sc2 partial ----
    float4 sc4;
    sc4.x = w0.x + w1.x + w2.x + w3.x + w4.x + w5.x + w6.x;
    sc4.y = w0.y + w1.y + w2.y + w3.y + w4.y + w5.y + w6.y;
    sc4.z = w0.z + w1.z + w2.z + w3.z + w4.z + w5.z + w6.z;
    sc4.w = w0.w + w1.w + w2.w + w3.w + w4.w + w5.w + w6.w;
    float sc2_l =
          w0.x*w0.x + w0.y*w0.y + w0.z*w0.z + w0.w*w0.w
        + w1.x*w1.x + w1.y*w1.y + w1.z*w1.z + w1.w*w1.w
        + w2.x*w2.x + w2.y*w2.y + w2.z*w2.z + w2.w*w2.w
        + w3.x*w3.x + w3.y*w3.y + w3.z*w3.z + w3.w*w3.w
        + w4.x*w4.x + w4.y*w4.y + w4.z*w4.z + w4.w*w4.w
        + w5.x*w5.x + w5.y*w5.y + w5.z*w5.z + w5.w*w5.w
        + w6.x*w6.x + w6.y*w6.y + w6.z*w6.z + w6.w*w6.w;

    scc[rowgrp][col4] = sc4;
    __syncthreads();

    float4 sC = {0.f, 0.f, 0.f, 0.f};
    #pragma unroll
    for (int k = 0; k < 16; ++k) {
        float4 v = scc[k][col4];
        sC.x += v.x; sC.y += v.y; sC.z += v.z; sC.w += v.w;
    }

    // ---- per-row math over this thread's 4 rows x 4 cols ----
    const float ff0 = f0.x*f0.x + f0.y*f0.y + f0.z*f0.z + f0.w*f0.w;
    const float ff1 = f1.x*f1.x + f1.y*f1.y + f1.z*f1.z + f1.w*f1.w;
    const float ff2 = f2.x*f2.x + f2.y*f2.y + f2.z*f2.z + f2.w*f2.w;
    const float ff3 = f3.x*f3.x + f3.y*f3.y + f3.z*f3.z + f3.w*f3.w;
    const float gg0 = g0.x*g0.x + g0.y*g0.y + g0.z*g0.z + g0.w*g0.w;
    const float gg1 = g1.x*g1.x + g1.y*g1.y + g1.z*g1.z + g1.w*g1.w;
    const float gg2 = g2.x*g2.x + g2.y*g2.y + g2.z*g2.z + g2.w*g2.w;
    const float gg3 = g3.x*g3.x + g3.y*g3.y + g3.z*g3.z + g3.w*g3.w;
    const float fg0 = f0.x*g0.x + f0.y*g0.y + f0.z*g0.z + f0.w*g0.w;
    const float fg1 = f1.x*g1.x + f1.y*g1.y + f1.z*g1.z + f1.w*g1.w;
    const float fg2 = f2.x*g2.x + f2.y*g2.y + f2.z*g2.z + f2.w*g2.w;
    const float fg3 = f3.x*g3.x + f3.y*g3.y + f3.z*g3.z + f3.w*g3.w;

    float intra_l = (ff0 + gg0 - 2.f*fg0) + (ff1 + gg1 - 2.f*fg1)
                  + (ff2 + gg2 - 2.f*fg2) + (ff3 + gg3 - 2.f*fg3);
    float sf2_l   = ff0 + ff1 + ff2 + ff3;

    float4 sF;
    sF.x = f0.x + f1.x + f2.x + f3.x;
    sF.y = f0.y + f1.y + f2.y + f3.y;
    sF.z = f0.z + f1.z + f2.z + f3.z;
    sF.w = f0.w + f1.w + f2.w + f3.w;
    float dot_l = sF.x*sC.x + sF.y*sC.y + sF.z*sC.z + sF.w*sC.w;

    float sc2c = (rc == 0) ? sc2_l : 0.f;

    #pragma unroll
    for (int off = 32; off > 0; off >>= 1) {
        intra_l += __shfl_xor(intra_l, off);
        sf2_l   += __shfl_xor(sf2_l,   off);
        dot_l   += __shfl_xor(dot_l,   off);
        sc2c    += __shfl_xor(sc2c,    off);
    }
    if (lane == 0) {
        swav[wave][0] = intra_l;
        swav[wave][1] = sf2_l;
        swav[wave][2] = dot_l;
        swav[wave][3] = sc2c;
    }
    __syncthreads();

    if (t == 0) {
        float4 s;
        s.x = swav[0][0] + swav[1][0] + swav[2][0] + swav[3][0];
        s.y = swav[0][1] + swav[1][1] + swav[2][1] + swav[3][1];
        s.z = swav[0][2] + swav[1][2] + swav[2][2] + swav[3][2];
        s.w = swav[0][3] + swav[1][3] + swav[2][3] + swav[3][3];
        ws[blockIdx.x] = s;
    }
}

__global__ __launch_bounds__(256) void ccl_final(
        const float4* __restrict__ ws, float* __restrict__ out,
        int B, int C)
{
    __shared__ float red[4][4];
    const int t    = threadIdx.x;
    const int lane = t & 63;
    const int wv   = t >> 6;

    float4 s = ws[t];   // 256 slots, one per main block
    float intra = s.x, sf2 = s.y, dot = s.z, sc2 = s.w;

    #pragma unroll
    for (int off = 32; off > 0; off >>= 1) {
        intra += __shfl_xor(intra, off);
        sf2   += __shfl_xor(sf2,   off);
        dot   += __shfl_xor(dot,   off);
        sc2   += __shfl_xor(sc2,   off);
    }
    if (lane == 0) {
        red[wv][0] = intra; red[wv][1] = sf2; red[wv][2] = dot; red[wv][3] = sc2;
    }
    __syncthreads();

    if (t == 0) {
        float Sin = red[0][0] + red[1][0] + red[2][0] + red[3][0];
        float Sf2 = red[0][1] + red[1][1] + red[2][1] + red[3][1];
        float Dot = red[0][2] + red[1][2] + red[2][2] + red[3][2];
        float Sc2 = red[0][3] + red[1][3] + red[2][3] + red[3][3];
        float total = (float)C * Sf2 + (float)B * Sc2 - 2.f * Dot;
        float inter = total - Sin;
        out[0] = 0.5f / (float)B * Sin / (inter + 1e-6f) / 0.1f;
    }
}

extern "C" void kernel_launch(void* const* d_in, const int* in_sizes, int n_in,
                              void* d_out, int out_size, void* d_ws, size_t ws_size,
                              hipStream_t stream) {
    const float* feat   = (const float*)d_in[0];
    const float* weight = (const float*)d_in[1];
    const int*   label  = (const int*)d_in[2];
    float* out = (float*)d_out;
    float4* ws = (float4*)d_ws;

    const int B = in_sizes[2];              // 2048
    const int D = in_sizes[0] / B;          // 512
    const int C = in_sizes[1] / D;          // 100
    // kernel is specialized for B=2048, D=512, C=100 (fixed by setup_inputs)

    ccl_main<<<256, 256, 0, stream>>>(feat, weight, label, ws);
    ccl_final<<<1, 256, 0, stream>>>(ws, out, B, C);
}